// Round 2
// baseline (737.168 us; speedup 1.0000x reference)
//
#include <hip/hip_runtime.h>
#include <stdint.h>

#define B_ 8
#define C_ 256
#define N_ 4096
#define M_ 4096
#define NT 64
#define MT 64
#define QP 264   // pitch in ushort (256 + 8 pad) -> 528B rows, 16B aligned
#define KP 264
#define VP 72    // sV pitch (64 + 8 pad)
#define PP 72

typedef __bf16 bf16x8 __attribute__((ext_vector_type(8)));
typedef float f32x4 __attribute__((ext_vector_type(4)));

__device__ __forceinline__ unsigned short f2bf(float f) {
    union { float f; unsigned u; } x; x.f = f;
    unsigned r = x.u + 0x7FFF + ((x.u >> 16) & 1);   // RNE
    return (unsigned short)(r >> 16);
}
__device__ __forceinline__ float bf2f(unsigned short s) {
    union { unsigned u; float f; } x; x.u = ((unsigned)s) << 16;
    return x.f;
}

// pre-pass 1: xs [B,C,M] f32 -> Kt_hi/Kt_lo [B,M,C] bf16 (transpose + split-convert)
__global__ __launch_bounds__(256) void kTranspose(const float* __restrict__ xs,
                                                  unsigned short* __restrict__ kthi,
                                                  unsigned short* __restrict__ ktlo) {
    __shared__ float tile[64][65];
    int b = blockIdx.z, m0 = blockIdx.x * 64, c0 = blockIdx.y * 64;
    int t = threadIdx.x;
    int cl = t >> 4, m4 = (t & 15) * 4;
#pragma unroll
    for (int i = 0; i < 4; i++) {
        int c = c0 + cl + i * 16;
        const float4 v = *(const float4*)(xs + ((size_t)(b * C_ + c) * M_) + m0 + m4);
        tile[m4 + 0][cl + i * 16] = v.x;
        tile[m4 + 1][cl + i * 16] = v.y;
        tile[m4 + 2][cl + i * 16] = v.z;
        tile[m4 + 3][cl + i * 16] = v.w;
    }
    __syncthreads();
    int ml = t >> 4, c4 = (t & 15) * 4;
#pragma unroll
    for (int i = 0; i < 4; i++) {
        int m = m0 + ml + i * 16;
        ushort4 ohi, olo;
        float x0 = tile[ml + i * 16][c4 + 0];
        float x1 = tile[ml + i * 16][c4 + 1];
        float x2 = tile[ml + i * 16][c4 + 2];
        float x3 = tile[ml + i * 16][c4 + 3];
        ohi.x = f2bf(x0); olo.x = f2bf(x0 - bf2f(ohi.x));
        ohi.y = f2bf(x1); olo.y = f2bf(x1 - bf2f(ohi.y));
        ohi.z = f2bf(x2); olo.z = f2bf(x2 - bf2f(ohi.z));
        ohi.w = f2bf(x3); olo.w = f2bf(x3 - bf2f(ohi.w));
        *(ushort4*)(kthi + ((size_t)(b * M_ + m) * C_) + c0 + c4) = ohi;
        *(ushort4*)(ktlo + ((size_t)(b * M_ + m) * C_) + c0 + c4) = olo;
    }
}

// pre-pass 2: ys f32 -> bf16, same [B,C,M] layout
__global__ __launch_bounds__(256) void kConvert(const float* __restrict__ ys,
                                                unsigned short* __restrict__ vb) {
    size_t i = ((size_t)blockIdx.x * 256 + threadIdx.x) * 4;
    float4 v = *(const float4*)(ys + i);
    ushort4 o;
    o.x = f2bf(v.x); o.y = f2bf(v.y); o.z = f2bf(v.z); o.w = f2bf(v.w);
    *(ushort4*)(vb + i) = o;
}

// main flash-attention kernel: one block per (batch, 64-query tile)
__global__ __launch_bounds__(256, 1) void kAttn(const float* __restrict__ h,
                                                const unsigned short* __restrict__ kthi,
                                                const unsigned short* __restrict__ ktlo,
                                                const unsigned short* __restrict__ vb,
                                                float* __restrict__ out) {
    // Region A: staging phase = Qhi|Qlo ; loop phase = Khi|Klo (NT==MT, QP==KP)
    __shared__ unsigned short sA[2 * NT * QP];
    __shared__ unsigned short sV[C_ * VP];   // [c][m] bf16
    __shared__ unsigned short sP[NT * PP];   // [n][m] bf16
    __shared__ float sAlpha[NT];
    __shared__ float sL[NT];

    const int t = threadIdx.x;
    const int w = t >> 6, lane = t & 63, quad = lane >> 4, l15 = lane & 15;
    const int bx = blockIdx.x;
    const int b = bx >> 6;            // N_/NT = 64 tiles per batch
    const int n0 = (bx & 63) * NT;

    const int nb = w * 16;   // this wave's S-row strip
    const int cb = w * 64;   // this wave's O-row (channel) strip

    // ---- stage Q transposed + split: sA = [Qhi | Qlo], [n][c] bf16 ----
    {
        int cl = t >> 4, n4 = (t & 15) * 4;
        for (int i = 0; i < 16; i++) {
            int c = i * 16 + cl;
            const float4 v = *(const float4*)(h + ((size_t)(b * C_ + c) * N_) + n0 + n4);
            float xv[4] = {v.x, v.y, v.z, v.w};
#pragma unroll
            for (int j = 0; j < 4; j++) {
                unsigned short hi = f2bf(xv[j]);
                unsigned short lo = f2bf(xv[j] - bf2f(hi));
                sA[(n4 + j) * QP + c] = hi;
                sA[NT * QP + (n4 + j) * QP + c] = lo;
            }
        }
    }
    __syncthreads();

    // ---- Q fragments to registers (fixed for whole m-loop) ----
    bf16x8 qhi[8], qlo[8];
#pragma unroll
    for (int ks = 0; ks < 8; ks++) {
        qhi[ks] = *(const bf16x8*)(sA + (nb + l15) * QP + ks * 32 + quad * 8);
        qlo[ks] = *(const bf16x8*)(sA + NT * QP + (nb + l15) * QP + ks * 32 + quad * 8);
    }

    f32x4 o[4][4];
#pragma unroll
    for (int i = 0; i < 4; i++)
#pragma unroll
        for (int j = 0; j < 4; j++)
            o[i][j] = (f32x4){0.f, 0.f, 0.f, 0.f};

    float mst[4], lst[4];
#pragma unroll
    for (int r = 0; r < 4; r++) { mst[r] = -3.0e38f; lst[r] = 0.f; }

    for (int m0i = 0; m0i < M_; m0i += MT) {
        // ensures: iter0 Q-fragment reads done; prev iter's PV reads of sV/sP done
        __syncthreads();

        // ---- stage K tile hi/lo + V tile ----
        {
            const unsigned short* srch = kthi + (size_t)(b * M_ + m0i) * C_;
            const unsigned short* srcl = ktlo + (size_t)(b * M_ + m0i) * C_;
#pragma unroll
            for (int i = 0; i < 8; i++) {
                int chunk = i * 256 + t;
                int ml = chunk >> 5, coff = (chunk & 31) * 8;
                *(bf16x8*)(sA + ml * KP + coff) =
                    *(const bf16x8*)(srch + (size_t)ml * C_ + coff);
                *(bf16x8*)(sA + MT * KP + ml * KP + coff) =
                    *(const bf16x8*)(srcl + (size_t)ml * C_ + coff);
            }
            const unsigned short* vsrc = vb + (size_t)b * C_ * M_ + m0i;
#pragma unroll
            for (int i = 0; i < 8; i++) {
                int chunk = i * 256 + t;
                int clr = chunk >> 3, moff = (chunk & 7) * 8;
                *(bf16x8*)(sV + clr * VP + moff) =
                    *(const bf16x8*)(vsrc + (size_t)clr * M_ + moff);
            }
        }
        __syncthreads();

        // ---- S = Q·K^T split-precision: Qhi·Khi + Qhi·Klo + Qlo·Khi ----
        f32x4 s[4];
#pragma unroll
        for (int mt = 0; mt < 4; mt++) s[mt] = (f32x4){0.f, 0.f, 0.f, 0.f};
#pragma unroll
        for (int ks = 0; ks < 8; ks++) {
#pragma unroll
            for (int mt = 0; mt < 4; mt++) {
                bf16x8 bkhi = *(const bf16x8*)(sA + (mt * 16 + l15) * KP + ks * 32 + quad * 8);
                bf16x8 bklo = *(const bf16x8*)(sA + MT * KP + (mt * 16 + l15) * KP + ks * 32 + quad * 8);
                s[mt] = __builtin_amdgcn_mfma_f32_16x16x32_bf16(qhi[ks], bkhi, s[mt], 0, 0, 0);
                s[mt] = __builtin_amdgcn_mfma_f32_16x16x32_bf16(qhi[ks], bklo, s[mt], 0, 0, 0);
                s[mt] = __builtin_amdgcn_mfma_f32_16x16x32_bf16(qlo[ks], bkhi, s[mt], 0, 0, 0);
            }
        }

        // ---- online softmax: rows nb + quad*4 + r, spread over 16 lanes ----
#pragma unroll
        for (int r = 0; r < 4; r++) {
            float rowmax = fmaxf(fmaxf(s[0][r], s[1][r]), fmaxf(s[2][r], s[3][r]));
#pragma unroll
            for (int off = 1; off < 16; off <<= 1)
                rowmax = fmaxf(rowmax, __shfl_xor(rowmax, off, 64));
            float mnew = fmaxf(mst[r], rowmax);
            float al = exp2f((mst[r] - mnew) * 1.44269504f);
            float rowsum = 0.f;
#pragma unroll
            for (int mt = 0; mt < 4; mt++) {
                float p = exp2f((s[mt][r] - mnew) * 1.44269504f);
                s[mt][r] = p;
                rowsum += p;
            }
#pragma unroll
            for (int off = 1; off < 16; off <<= 1)
                rowsum += __shfl_xor(rowsum, off, 64);
            lst[r] = lst[r] * al + rowsum;
            mst[r] = mnew;
            int row = nb + quad * 4 + r;
            if (l15 == 0) sAlpha[row] = al;
#pragma unroll
            for (int mt = 0; mt < 4; mt++)
                sP[row * PP + mt * 16 + l15] = f2bf(s[mt][r]);
        }
        __syncthreads();

        // ---- rescale O by alpha[n], then O += V·P^T ----
        float av[4];
#pragma unroll
        for (int nt = 0; nt < 4; nt++) av[nt] = sAlpha[nt * 16 + l15];
#pragma unroll
        for (int ct = 0; ct < 4; ct++)
#pragma unroll
            for (int nt = 0; nt < 4; nt++) {
                o[ct][nt][0] *= av[nt];
                o[ct][nt][1] *= av[nt];
                o[ct][nt][2] *= av[nt];
                o[ct][nt][3] *= av[nt];
            }
#pragma unroll
        for (int ks = 0; ks < 2; ks++) {
            bf16x8 aV[4];
#pragma unroll
            for (int ct = 0; ct < 4; ct++)
                aV[ct] = *(const bf16x8*)(sV + (cb + ct * 16 + l15) * VP + ks * 32 + quad * 8);
#pragma unroll
            for (int nt = 0; nt < 4; nt++) {
                bf16x8 bp = *(const bf16x8*)(sP + (nt * 16 + l15) * PP + ks * 32 + quad * 8);
#pragma unroll
                for (int ct = 0; ct < 4; ct++)
                    o[ct][nt] = __builtin_amdgcn_mfma_f32_16x16x32_bf16(aV[ct], bp, o[ct][nt], 0, 0, 0);
            }
        }
    }

    // ---- epilogue: divide by l[n], write out[b][c][n0+n] ----
    if (l15 == 0) {
#pragma unroll
        for (int r = 0; r < 4; r++) sL[nb + quad * 4 + r] = lst[r];
    }
    __syncthreads();
    float linv[4];
#pragma unroll
    for (int nt = 0; nt < 4; nt++) linv[nt] = 1.0f / sL[nt * 16 + l15];
#pragma unroll
    for (int ct = 0; ct < 4; ct++)
#pragma unroll
        for (int nt = 0; nt < 4; nt++)
#pragma unroll
            for (int r = 0; r < 4; r++) {
                int c = cb + ct * 16 + quad * 4 + r;
                out[((size_t)(b * C_ + c)) * N_ + n0 + nt * 16 + l15] = o[ct][nt][r] * linv[nt];
            }
}

extern "C" void kernel_launch(void* const* d_in, const int* in_sizes, int n_in,
                              void* d_out, int out_size, void* d_ws, size_t ws_size,
                              hipStream_t stream) {
    const float* h  = (const float*)d_in[0];
    const float* xs = (const float*)d_in[1];
    const float* ys = (const float*)d_in[2];
    float* out = (float*)d_out;

    unsigned short* kthi = (unsigned short*)d_ws;                     // [B,M,C] bf16: 16 MB
    unsigned short* ktlo = kthi + (size_t)B_ * M_ * C_;               // [B,M,C] bf16: 16 MB
    unsigned short* vbb  = ktlo + (size_t)B_ * M_ * C_;               // [B,C,M] bf16: 16 MB

    kTranspose<<<dim3(M_ / 64, C_ / 64, B_), 256, 0, stream>>>(xs, kthi, ktlo);
    kConvert<<<dim3((B_ * C_ * M_) / (4 * 256)), 256, 0, stream>>>(ys, vbb);
    kAttn<<<dim3(B_ * (N_ / NT)), 256, 0, stream>>>(h, kthi, ktlo, vbb, out);
}

// Round 3
// 380.333 us; speedup vs baseline: 1.9382x; 1.9382x over previous
//
#include <hip/hip_runtime.h>
#include <stdint.h>

#define B_ 8
#define C_ 256
#define N_ 4096
#define M_ 4096
#define NT 64
#define MT 64
#define PP 72    // sP pitch (64 + 8 pad), 16B-aligned odd multiple of 16B

typedef _Float16 f16x8 __attribute__((ext_vector_type(8)));
typedef _Float16 f16x4 __attribute__((ext_vector_type(4)));
typedef float f32x4 __attribute__((ext_vector_type(4)));

__device__ __forceinline__ void async16(const _Float16* g, _Float16* l) {
    __builtin_amdgcn_global_load_lds(
        (const __attribute__((address_space(1))) void*)g,
        (__attribute__((address_space(3))) void*)l, 16, 0, 0);
}

// pre-pass 1: xs [B,C,M] f32 -> Kt [B,M,C] fp16 (transpose + convert)
__global__ __launch_bounds__(256) void kTranspose(const float* __restrict__ xs,
                                                  _Float16* __restrict__ kt) {
    __shared__ float tile[64][65];
    int b = blockIdx.z, m0 = blockIdx.x * 64, c0 = blockIdx.y * 64;
    int t = threadIdx.x;
    int cl = t >> 4, m4 = (t & 15) * 4;
#pragma unroll
    for (int i = 0; i < 4; i++) {
        int c = c0 + cl + i * 16;
        const float4 v = *(const float4*)(xs + ((size_t)(b * C_ + c) * M_) + m0 + m4);
        tile[m4 + 0][cl + i * 16] = v.x;
        tile[m4 + 1][cl + i * 16] = v.y;
        tile[m4 + 2][cl + i * 16] = v.z;
        tile[m4 + 3][cl + i * 16] = v.w;
    }
    __syncthreads();
    int ml = t >> 4, c4 = (t & 15) * 4;
#pragma unroll
    for (int i = 0; i < 4; i++) {
        int m = m0 + ml + i * 16;
        f16x4 o;
        o[0] = (_Float16)tile[ml + i * 16][c4 + 0];
        o[1] = (_Float16)tile[ml + i * 16][c4 + 1];
        o[2] = (_Float16)tile[ml + i * 16][c4 + 2];
        o[3] = (_Float16)tile[ml + i * 16][c4 + 3];
        *(f16x4*)(kt + ((size_t)(b * M_ + m) * C_) + c0 + c4) = o;
    }
}

// pre-pass 2: ys f32 -> fp16, same [B,C,M] layout
__global__ __launch_bounds__(256) void kConvert(const float* __restrict__ ys,
                                                _Float16* __restrict__ vb) {
    size_t i = ((size_t)blockIdx.x * 256 + threadIdx.x) * 4;
    float4 v = *(const float4*)(ys + i);
    f16x4 o;
    o[0] = (_Float16)v.x; o[1] = (_Float16)v.y;
    o[2] = (_Float16)v.z; o[3] = (_Float16)v.w;
    *(f16x4*)(vb + i) = o;
}

// main flash-attention kernel: one block per (batch, 64-query tile), 2 blocks/CU
__global__ __launch_bounds__(256, 2) void kAttn(const float* __restrict__ h,
                                                const _Float16* __restrict__ kt,
                                                const _Float16* __restrict__ vb,
                                                float* __restrict__ out) {
    // sK: [row][256] fp16, 16B chunks XOR-swizzled by (row&31). Holds Q during init.
    __shared__ _Float16 sK[MT * 256];       // 32 KB
    __shared__ _Float16 sV[C_ * 64];        // 32 KB, chunks swizzled by (row&7)
    __shared__ _Float16 sP[NT * PP];        // 9.2 KB
    __shared__ float sAlpha[NT];
    __shared__ float sL[NT];

    const int t = threadIdx.x;
    const int w = t >> 6, lane = t & 63, quad = lane >> 4, l15 = lane & 15;
    const int bx = blockIdx.x;
    const int b = bx >> 6;            // N_/NT = 64 tiles per batch
    const int n0 = (bx & 63) * NT;

    const int nb = w * 16;   // this wave's S-row strip
    const int cb = w * 64;   // this wave's O-row (channel) strip

    // ---- stage Q transposed into sK (swizzled): sK[n][c] = fp16(h[b][c][n0+n]) ----
    {
        int cl = t >> 4, n4 = (t & 15) * 4;
        for (int i = 0; i < 16; i++) {
            int c = i * 16 + cl;
            const float4 v = *(const float4*)(h + ((size_t)(b * C_ + c) * N_) + n0 + n4);
            float xv[4] = {v.x, v.y, v.z, v.w};
#pragma unroll
            for (int j = 0; j < 4; j++) {
                int row = n4 + j;
                sK[row * 256 + (((c >> 3) ^ (row & 31)) << 3) + (c & 7)] = (_Float16)xv[j];
            }
        }
    }
    __syncthreads();

    // ---- Q fragments to registers (fixed for whole m-loop) ----
    f16x8 qf[8];
    {
        int qrow = nb + l15;
#pragma unroll
        for (int ks = 0; ks < 8; ks++)
            qf[ks] = *(const f16x8*)(sK + qrow * 256 + ((((ks << 2) + quad) ^ (qrow & 31)) << 3));
    }

    f32x4 o[4][4];
#pragma unroll
    for (int i = 0; i < 4; i++)
#pragma unroll
        for (int j = 0; j < 4; j++)
            o[i][j] = (f32x4){0.f, 0.f, 0.f, 0.f};

    float mst[4], lst[4];
#pragma unroll
    for (int r = 0; r < 4; r++) { mst[r] = -3.0e38f; lst[r] = 0.f; }

    const _Float16* srcKb = kt + (size_t)b * M_ * C_;
    const _Float16* srcVb = vb + (size_t)b * C_ * M_;

    for (int m0i = 0; m0i < M_; m0i += MT) {
        // all waves done reading sK (Q frags / prev K) and sV/sP before restage
        __syncthreads();

        // ---- K tile: async global->LDS, swizzled. Wave w covers rows [w*16, w*16+16) ----
        {
            const _Float16* srcK = srcKb + (size_t)m0i * C_;
#pragma unroll
            for (int j = 0; j < 8; j++) {
                int row = w * 16 + j * 2 + (lane >> 5);
                int logi = (lane & 31) ^ (row & 31);
                async16(srcK + (size_t)row * C_ + logi * 8, sK + (w * 16 + j * 2) * 256);
            }
            // V tile: wave w covers rows [w*64, w*64+64)
#pragma unroll
            for (int j = 0; j < 8; j++) {
                int row = w * 64 + j * 8 + (lane >> 3);
                int logi = (lane & 7) ^ (row & 7);
                async16(srcVb + (size_t)row * M_ + m0i + logi * 8, sV + (w * 64 + j * 8) * 64);
            }
        }
        __syncthreads();

        // ---- S = Q·K^T : wave rows [nb, nb+16), cols [0,64) ----
        f32x4 s[4];
#pragma unroll
        for (int mt = 0; mt < 4; mt++) s[mt] = (f32x4){0.f, 0.f, 0.f, 0.f};
#pragma unroll
        for (int ks = 0; ks < 8; ks++) {
#pragma unroll
            for (int mt = 0; mt < 4; mt++) {
                int krow = mt * 16 + l15;
                f16x8 bk = *(const f16x8*)(sK + krow * 256 + ((((ks << 2) + quad) ^ (krow & 31)) << 3));
                s[mt] = __builtin_amdgcn_mfma_f32_16x16x32_f16(qf[ks], bk, s[mt], 0, 0, 0);
            }
        }

        // ---- online softmax: rows nb + quad*4 + r, spread over 16 lanes ----
#pragma unroll
        for (int r = 0; r < 4; r++) {
            float rowmax = fmaxf(fmaxf(s[0][r], s[1][r]), fmaxf(s[2][r], s[3][r]));
#pragma unroll
            for (int off = 1; off < 16; off <<= 1)
                rowmax = fmaxf(rowmax, __shfl_xor(rowmax, off, 64));
            float mnew = fmaxf(mst[r], rowmax);
            float al = exp2f((mst[r] - mnew) * 1.44269504f);
            float rowsum = 0.f;
#pragma unroll
            for (int mt = 0; mt < 4; mt++) {
                float p = exp2f((s[mt][r] - mnew) * 1.44269504f);
                s[mt][r] = p;
                rowsum += p;
            }
#pragma unroll
            for (int off = 1; off < 16; off <<= 1)
                rowsum += __shfl_xor(rowsum, off, 64);
            lst[r] = lst[r] * al + rowsum;
            mst[r] = mnew;
            int row = nb + quad * 4 + r;
            if (l15 == 0) sAlpha[row] = al;
#pragma unroll
            for (int mt = 0; mt < 4; mt++)
                sP[row * PP + mt * 16 + l15] = (_Float16)s[mt][r];
        }
        __syncthreads();

        // ---- rescale O by alpha[n], then O += V·P^T ----
        float av[4];
#pragma unroll
        for (int nt = 0; nt < 4; nt++) av[nt] = sAlpha[nt * 16 + l15];
#pragma unroll
        for (int ct = 0; ct < 4; ct++)
#pragma unroll
            for (int nt = 0; nt < 4; nt++) {
                o[ct][nt][0] *= av[nt];
                o[ct][nt][1] *= av[nt];
                o[ct][nt][2] *= av[nt];
                o[ct][nt][3] *= av[nt];
            }
#pragma unroll
        for (int ks = 0; ks < 2; ks++) {
            f16x8 aV[4];
#pragma unroll
            for (int ct = 0; ct < 4; ct++) {
                int vrow = cb + ct * 16 + l15;
                aV[ct] = *(const f16x8*)(sV + vrow * 64 + ((((ks << 2) + quad) ^ (vrow & 7)) << 3));
            }
#pragma unroll
            for (int nt = 0; nt < 4; nt++) {
                f16x8 bp = *(const f16x8*)(sP + (nt * 16 + l15) * PP + ks * 32 + quad * 8);
#pragma unroll
                for (int ct = 0; ct < 4; ct++)
                    o[ct][nt] = __builtin_amdgcn_mfma_f32_16x16x32_f16(aV[ct], bp, o[ct][nt], 0, 0, 0);
            }
        }
    }

    // ---- epilogue: divide by l[n], write out[b][c][n0+n] ----
    if (l15 == 0) {
#pragma unroll
        for (int r = 0; r < 4; r++) sL[nb + quad * 4 + r] = lst[r];
    }
    __syncthreads();
    float linv[4];
#pragma unroll
    for (int nt = 0; nt < 4; nt++) linv[nt] = 1.0f / sL[nt * 16 + l15];
#pragma unroll
    for (int ct = 0; ct < 4; ct++)
#pragma unroll
        for (int nt = 0; nt < 4; nt++)
#pragma unroll
            for (int r = 0; r < 4; r++) {
                int c = cb + ct * 16 + quad * 4 + r;
                out[((size_t)(b * C_ + c)) * N_ + n0 + nt * 16 + l15] = o[ct][nt][r] * linv[nt];
            }
}

extern "C" void kernel_launch(void* const* d_in, const int* in_sizes, int n_in,
                              void* d_out, int out_size, void* d_ws, size_t ws_size,
                              hipStream_t stream) {
    const float* h  = (const float*)d_in[0];
    const float* xs = (const float*)d_in[1];
    const float* ys = (const float*)d_in[2];
    float* out = (float*)d_out;

    _Float16* kt  = (_Float16*)d_ws;                    // [B,M,C] fp16: 16 MB
    _Float16* vbb = kt + (size_t)B_ * M_ * C_;          // [B,C,M] fp16: 16 MB

    kTranspose<<<dim3(M_ / 64, C_ / 64, B_), 256, 0, stream>>>(xs, kt);
    kConvert<<<dim3((B_ * C_ * M_) / (4 * 256)), 256, 0, stream>>>(ys, vbb);
    kAttn<<<dim3(B_ * (N_ / NT)), 256, 0, stream>>>(h, kt, vbb, out);
}

// Round 4
// 356.727 us; speedup vs baseline: 2.0665x; 1.0662x over previous
//
#include <hip/hip_runtime.h>
#include <stdint.h>

#define B_ 8
#define C_ 256
#define N_ 4096
#define M_ 4096
#define NT 64
#define MT 64
#define PP 72    // sP pitch (64 + 8 pad) halves; 144B rows
#define L2E 1.44269504f

typedef _Float16 f16x8 __attribute__((ext_vector_type(8)));
typedef _Float16 f16x4 __attribute__((ext_vector_type(4)));
typedef float f32x4 __attribute__((ext_vector_type(4)));

__device__ __forceinline__ void async16(const _Float16* g, _Float16* l) {
    __builtin_amdgcn_global_load_lds(
        (const __attribute__((address_space(1))) void*)g,
        (__attribute__((address_space(3))) void*)l, 16, 0, 0);
}

// fused pre-pass: blocks [0,2048) transpose xs -> kt [B,M,C] fp16;
//                 blocks [2048,10240) convert ys -> vb [B,C,M] fp16
__global__ __launch_bounds__(256) void kPre(const float* __restrict__ xs,
                                            const float* __restrict__ ys,
                                            _Float16* __restrict__ kt,
                                            _Float16* __restrict__ vb) {
    int bx = blockIdx.x;
    int t = threadIdx.x;
    if (bx < 2048) {
        __shared__ float tile[64][65];
        int b = bx >> 8, rem = bx & 255;
        int c0 = (rem >> 6) * 64, m0 = (rem & 63) * 64;
        int cl = t >> 4, m4 = (t & 15) * 4;
#pragma unroll
        for (int i = 0; i < 4; i++) {
            int c = c0 + cl + i * 16;
            const float4 v = *(const float4*)(xs + ((size_t)(b * C_ + c) * M_) + m0 + m4);
            tile[m4 + 0][cl + i * 16] = v.x;
            tile[m4 + 1][cl + i * 16] = v.y;
            tile[m4 + 2][cl + i * 16] = v.z;
            tile[m4 + 3][cl + i * 16] = v.w;
        }
        __syncthreads();
        int ml = t >> 4, c4 = (t & 15) * 4;
#pragma unroll
        for (int i = 0; i < 4; i++) {
            int m = m0 + ml + i * 16;
            f16x4 o;
            o[0] = (_Float16)tile[ml + i * 16][c4 + 0];
            o[1] = (_Float16)tile[ml + i * 16][c4 + 1];
            o[2] = (_Float16)tile[ml + i * 16][c4 + 2];
            o[3] = (_Float16)tile[ml + i * 16][c4 + 3];
            *(f16x4*)(kt + ((size_t)(b * M_ + m) * C_) + c0 + c4) = o;
        }
    } else {
        size_t i = ((size_t)(bx - 2048) * 256 + t) * 4;
        float4 v = *(const float4*)(ys + i);
        f16x4 o;
        o[0] = (_Float16)v.x; o[1] = (_Float16)v.y;
        o[2] = (_Float16)v.z; o[3] = (_Float16)v.w;
        *(f16x4*)(vb + i) = o;
    }
}

// flash-attention: one block per (batch, 64-query tile), 2 blocks/CU
__global__ __launch_bounds__(256, 2) void kAttn(const float* __restrict__ h,
                                                const _Float16* __restrict__ kt,
                                                const _Float16* __restrict__ vb,
                                                float* __restrict__ out) {
    // sK[buf]: [row][256] fp16, 16B chunks XOR-swizzled by (row&31). sK[1] holds Q in prologue.
    __shared__ _Float16 sK[2][MT * 256];     // 64 KB
    __shared__ _Float16 sP[NT * PP];         // 9.2 KB
    __shared__ float sAlpha[NT];
    __shared__ float sL[NT];
    __shared__ int sFlag[2];

    const int t = threadIdx.x;
    const int w = t >> 6, lane = t & 63, quad = lane >> 4, l15 = lane & 15;
    const int b = blockIdx.x >> 6;
    const int n0 = (blockIdx.x & 63) * NT;
    const int nb = w * 16;   // wave's S-row strip
    const int cb = w * 64;   // wave's O-channel strip

    const _Float16* srcKb = kt + (size_t)b * M_ * C_;
    const _Float16* srcVb = vb + (size_t)b * C_ * M_;

    if (t == 0) { sFlag[0] = 0; sFlag[1] = 0; }

    // ---- stage Q (transposed+swizzled) into sK[1]; issue K tile 0 into sK[0] ----
    {
        int cl = t >> 4, n4 = (t & 15) * 4;
        for (int i = 0; i < 16; i++) {
            int c = i * 16 + cl;
            const float4 v = *(const float4*)(h + ((size_t)(b * C_ + c) * N_) + n0 + n4);
            float xv[4] = {v.x, v.y, v.z, v.w};
#pragma unroll
            for (int j = 0; j < 4; j++) {
                int row = n4 + j;
                sK[1][row * 256 + (((c >> 3) ^ (row & 31)) << 3) + (c & 7)] = (_Float16)xv[j];
            }
        }
#pragma unroll
        for (int j = 0; j < 8; j++) {
            int row = w * 16 + j * 2 + (lane >> 5);
            int logi = (lane & 31) ^ (row & 31);
            async16(srcKb + (size_t)row * C_ + logi * 8, &sK[0][(w * 16 + j * 2) * 256]);
        }
    }
    __syncthreads();

    // ---- Q fragments to registers (fixed for whole m-loop); sK[1] free after loop-top barrier ----
    f16x8 qf[8];
    {
        int qrow = nb + l15;
#pragma unroll
        for (int ks = 0; ks < 8; ks++)
            qf[ks] = *(const f16x8*)(&sK[1][qrow * 256 + ((((ks << 2) + quad) ^ (qrow & 31)) << 3)]);
    }

    f32x4 o[4][4];
#pragma unroll
    for (int i = 0; i < 4; i++)
#pragma unroll
        for (int j = 0; j < 4; j++)
            o[i][j] = (f32x4){0.f, 0.f, 0.f, 0.f};

    float mst[4], lp[4];
#pragma unroll
    for (int r = 0; r < 4; r++) { mst[r] = -3.0e38f; lp[r] = 0.f; }

    for (int it = 0; it < M_ / MT; it++) {
        const int cur = it & 1, nxt = cur ^ 1;
        const int m0i = it * MT;
        // A: K-it LDS-writes visible; PV-(it-1) done with sP; S-(it-1)/qf done with sK[nxt]
        __syncthreads();

        if (t == 0) sFlag[nxt] = 0;   // armed for iteration it+1

        // issue K-(it+1) into the buffer S-(it-1) just finished reading
        if (it + 1 < M_ / MT) {
            const _Float16* srcK = srcKb + (size_t)(m0i + MT) * C_;
#pragma unroll
            for (int j = 0; j < 8; j++) {
                int row = w * 16 + j * 2 + (lane >> 5);
                int logi = (lane & 31) ^ (row & 31);
                async16(srcK + (size_t)row * C_ + logi * 8, &sK[nxt][(w * 16 + j * 2) * 256]);
            }
        }

        // V fragments for this tile: direct global->reg (wave-exclusive slice, full 64B lines)
        f16x8 vf[2][4];
#pragma unroll
        for (int ks = 0; ks < 2; ks++)
#pragma unroll
            for (int ct = 0; ct < 4; ct++) {
                int vrow = cb + ct * 16 + l15;
                vf[ks][ct] = *(const f16x8*)(srcVb + (size_t)vrow * M_ + m0i + ks * 32 + quad * 8);
            }

        // ---- S = Q·K^T : wave rows [nb,nb+16) x cols [0,64) ----
        f32x4 s[4];
#pragma unroll
        for (int mt = 0; mt < 4; mt++) s[mt] = (f32x4){0.f, 0.f, 0.f, 0.f};
#pragma unroll
        for (int ks = 0; ks < 8; ks++) {
#pragma unroll
            for (int mt = 0; mt < 4; mt++) {
                int krow = mt * 16 + l15;
                f16x8 bk = *(const f16x8*)(&sK[cur][krow * 256 + ((((ks << 2) + quad) ^ (krow & 31)) << 3)]);
                s[mt] = __builtin_amdgcn_mfma_f32_16x16x32_f16(qf[ks], bk, s[mt], 0, 0, 0);
            }
        }

        // ---- online softmax (per-row max; deferred l; conditional alpha) ----
#pragma unroll
        for (int r = 0; r < 4; r++) {
            float rowmax = fmaxf(fmaxf(s[0][r], s[1][r]), fmaxf(s[2][r], s[3][r]));
#pragma unroll
            for (int off = 1; off < 16; off <<= 1)
                rowmax = fmaxf(rowmax, __shfl_xor(rowmax, off, 64));
            float al = 1.0f;
            if (rowmax > mst[r]) {
                al = exp2f((mst[r] - rowmax) * L2E);
                mst[r] = rowmax;
            }
            float psum = 0.f;
#pragma unroll
            for (int mt = 0; mt < 4; mt++) {
                float p = exp2f((s[mt][r] - mst[r]) * L2E);
                s[mt][r] = p;
                psum += p;
            }
            lp[r] = lp[r] * al + psum;
            int row = nb + quad * 4 + r;
            if (l15 == 0) {
                sAlpha[row] = al;
                if (al != 1.0f) atomicOr(&sFlag[cur], 1);
            }
#pragma unroll
            for (int mt = 0; mt < 4; mt++)
                sP[row * PP + mt * 16 + l15] = (_Float16)s[mt][r];
        }
        // B: P + alphas + flag visible
        __syncthreads();

        // ---- rescale O only if some row's max moved this tile ----
        if (sFlag[cur]) {
            float av[4];
#pragma unroll
            for (int nt = 0; nt < 4; nt++) av[nt] = sAlpha[nt * 16 + l15];
#pragma unroll
            for (int ct = 0; ct < 4; ct++)
#pragma unroll
                for (int nt = 0; nt < 4; nt++) {
                    o[ct][nt][0] *= av[nt];
                    o[ct][nt][1] *= av[nt];
                    o[ct][nt][2] *= av[nt];
                    o[ct][nt][3] *= av[nt];
                }
        }

        // ---- O += V·P^T ----
#pragma unroll
        for (int ks = 0; ks < 2; ks++) {
#pragma unroll
            for (int nt = 0; nt < 4; nt++) {
                f16x8 bp = *(const f16x8*)(sP + (nt * 16 + l15) * PP + ks * 32 + quad * 8);
#pragma unroll
                for (int ct = 0; ct < 4; ct++)
                    o[ct][nt] = __builtin_amdgcn_mfma_f32_16x16x32_f16(vf[ks][ct], bp, o[ct][nt], 0, 0, 0);
            }
        }
    }

    // ---- epilogue: reduce deferred l across the 16-lane row group, divide, store ----
#pragma unroll
    for (int r = 0; r < 4; r++) {
#pragma unroll
        for (int off = 1; off < 16; off <<= 1)
            lp[r] += __shfl_xor(lp[r], off, 64);
        if (l15 == 0) sL[nb + quad * 4 + r] = lp[r];
    }
    __syncthreads();
    float linv[4];
#pragma unroll
    for (int nt = 0; nt < 4; nt++) linv[nt] = 1.0f / sL[nt * 16 + l15];
#pragma unroll
    for (int ct = 0; ct < 4; ct++)
#pragma unroll
        for (int nt = 0; nt < 4; nt++)
#pragma unroll
            for (int r = 0; r < 4; r++) {
                int c = cb + ct * 16 + quad * 4 + r;
                out[((size_t)(b * C_ + c)) * N_ + n0 + nt * 16 + l15] = o[ct][nt][r] * linv[nt];
            }
}

extern "C" void kernel_launch(void* const* d_in, const int* in_sizes, int n_in,
                              void* d_out, int out_size, void* d_ws, size_t ws_size,
                              hipStream_t stream) {
    const float* h  = (const float*)d_in[0];
    const float* xs = (const float*)d_in[1];
    const float* ys = (const float*)d_in[2];
    float* out = (float*)d_out;

    _Float16* kt  = (_Float16*)d_ws;                    // [B,M,C] fp16: 16 MB
    _Float16* vbb = kt + (size_t)B_ * M_ * C_;          // [B,C,M] fp16: 16 MB

    kPre<<<dim3(2048 + 8192), 256, 0, stream>>>(xs, ys, kt, vbb);
    kAttn<<<dim3(B_ * (N_ / NT)), 256, 0, stream>>>(h, kt, vbb, out);
}